// Round 7
// baseline (211.637 us; speedup 1.0000x reference)
//
#include <hip/hip_runtime.h>

#define NGRAPH 16384
#define NNODE  32
#define EMB    64
#define HIDDIM 2048
#define ETOT   4194304      // NTOT * 8
#define EPG    256          // edges per graph (contiguous block per graph)

typedef __attribute__((ext_vector_type(8))) short bf16x8_t;
typedef __attribute__((ext_vector_type(8))) unsigned short u16x8_t;
typedef __attribute__((ext_vector_type(4))) float f32x4_t;
typedef __attribute__((ext_vector_type(16))) float f32x16_t;

__device__ __forceinline__ unsigned short f2bf(float v) {
  unsigned int u = __float_as_uint(v);
  u += 0x7fffu + ((u >> 16) & 1u);
  return (unsigned short)(u >> 16);
}
__device__ __forceinline__ float bf2f(unsigned short u) {
  return __uint_as_float(((unsigned int)u) << 16);
}
__device__ __forceinline__ unsigned int cvtpk(float lo, float hi) {
  unsigned int r;
  asm("v_cvt_pk_bf16_f32 %0, %1, %2" : "=v"(r) : "v"(lo), "v"(hi));
  return r;
}
__device__ __forceinline__ bf16x8_t pack8(float4 a, float4 b) {
  union { unsigned int u[4]; bf16x8_t v; } r;
  r.u[0] = cvtpk(a.x, a.y); r.u[1] = cvtpk(a.z, a.w);
  r.u[2] = cvtpk(b.x, b.y); r.u[3] = cvtpk(b.z, b.w);
  return r.v;
}

#define GLDS(SRC, DST)                                                          \
  __builtin_amdgcn_global_load_lds(                                             \
      (const __attribute__((address_space(1))) void*)(SRC),                     \
      (__attribute__((address_space(3))) void*)(DST), 16, 0, 0)

// ---------------------------------------------------------------------------
// Kernel 1: W1 fp32 -> bf16 with column permutation k' = feat*32+node
// ---------------------------------------------------------------------------
__global__ __launch_bounds__(256) void cvt_w1(const float* __restrict__ W,
                                              unsigned short* __restrict__ Wb) {
  __shared__ float row[HIDDIM];
  const int r = blockIdx.x, t = threadIdx.x;
  const float4* p = (const float4*)(W + (size_t)r * HIDDIM);
  *(float4*)&row[t * 8]     = p[t * 2];
  *(float4*)&row[t * 8 + 4] = p[t * 2 + 1];
  __syncthreads();
  const int feat = t >> 2, nb = (t & 3) * 8;   // k' = t*8+j -> feat fixed, node nb+j
  u16x8_t o;
  #pragma unroll
  for (int j = 0; j < 8; ++j) o[j] = f2bf(row[(nb + j) * 64 + feat]);
  *(u16x8_t*)(Wb + (size_t)r * HIDDIM + t * 8) = o;
}

// ---------------------------------------------------------------------------
// Kernel 2: fused GCNConv + ReLU, ONE WAVE PER GRAPH (unchanged from round 6)
// ---------------------------------------------------------------------------
__global__ __launch_bounds__(256, 4) void gcn_kernel(const float* __restrict__ x,
                                                     const float* __restrict__ Wc,
                                                     const float* __restrict__ bc,
                                                     const int* __restrict__ ei,
                                                     unsigned short* __restrict__ abf) {
  __shared__ __align__(16) char smem[40960];     // 4 waves x 10240 B
  const int wv = threadIdx.x >> 6, lane = threadIdx.x & 63;
  const int g = blockIdx.x * 4 + wv;
  char* my = smem + wv * 10240;
  unsigned int*   adjcnt = (unsigned int*)my;            // u32 [32][32], 4096B
  unsigned short* adjb   = (unsigned short*)my;          // bf16 [32][40] (overlays)
  unsigned short* outT   = (unsigned short*)my;          // bf16 [64][40] (overlays)
  unsigned short* hT     = (unsigned short*)(my + 5120); // bf16 [64][40]
  const int lr = lane & 15, lk = lane >> 4;

  const float* xg = x + (size_t)g * (NNODE * EMB);
  float4 xr[2][2][2];
  #pragma unroll
  for (int mt = 0; mt < 2; ++mt)
    #pragma unroll
    for (int kk = 0; kk < 2; ++kk) {
      const float* p = xg + (mt * 16 + lr) * EMB + kk * 32 + lk * 8;
      xr[mt][kk][0] = *(const float4*)p;
      xr[mt][kk][1] = *(const float4*)(p + 4);
    }

  int sl[4], dl[4];
  #pragma unroll
  for (int j = 0; j < 4; ++j) {
    sl[j] = ei[(size_t)g * EPG + j * 64 + lane] - g * NNODE;
    dl[j] = ei[(size_t)ETOT + (size_t)g * EPG + j * 64 + lane] - g * NNODE;
  }

  {
    uint4 z = {0u, 0u, 0u, 0u};
    #pragma unroll
    for (int i = 0; i < 4; ++i) *(uint4*)&adjcnt[lane * 16 + i * 4] = z;
  }
  asm volatile("" ::: "memory");
  #pragma unroll
  for (int j = 0; j < 4; ++j) atomicAdd(&adjcnt[dl[j] * 32 + sl[j]], 1u);
  asm volatile("" ::: "memory");

  const int rr = lane >> 1, hh = lane & 1;
  uint4 c[4];
  unsigned int cs = 0;
  #pragma unroll
  for (int i = 0; i < 4; ++i) {
    c[i] = *(const uint4*)&adjcnt[rr * 32 + hh * 16 + i * 4];
    cs += c[i].x + c[i].y + c[i].z + c[i].w;
  }
  cs += (unsigned int)__shfl_xor((int)cs, 1);
  const float dinvr = rsqrtf(1.0f + (float)cs);
  asm volatile("" ::: "memory");
  {
    float vals[16];
    #pragma unroll
    for (int i = 0; i < 4; ++i) {
      const unsigned int cc[4] = {c[i].x, c[i].y, c[i].z, c[i].w};
      #pragma unroll
      for (int e = 0; e < 4; ++e) {
        const int s = hh * 16 + i * 4 + e;
        const float ds = __shfl(dinvr, s * 2);
        const float cnt = (float)cc[e] + ((s == rr) ? 1.0f : 0.0f);
        vals[i * 4 + e] = cnt * dinvr * ds;
      }
    }
    union { unsigned int u[8]; u16x8_t v[2]; } pk;
    #pragma unroll
    for (int i = 0; i < 8; ++i) pk.u[i] = cvtpk(vals[2 * i], vals[2 * i + 1]);
    *(u16x8_t*)&adjb[rr * 40 + hh * 16]     = pk.v[0];
    *(u16x8_t*)&adjb[rr * 40 + hh * 16 + 8] = pk.v[1];
  }

  bf16x8_t xa[2][2];
  #pragma unroll
  for (int mt = 0; mt < 2; ++mt)
    #pragma unroll
    for (int kk = 0; kk < 2; ++kk) xa[mt][kk] = pack8(xr[mt][kk][0], xr[mt][kk][1]);
  f32x4_t hc[2][4];
  #pragma unroll
  for (int mt = 0; mt < 2; ++mt)
    #pragma unroll
    for (int nt = 0; nt < 4; ++nt) hc[mt][nt] = (f32x4_t){0.f, 0.f, 0.f, 0.f};
  #pragma unroll
  for (int nt = 0; nt < 4; ++nt)
    #pragma unroll
    for (int kk = 0; kk < 2; ++kk) {
      const float* p = Wc + (nt * 16 + lr) * EMB + kk * 32 + lk * 8;
      const bf16x8_t wb = pack8(*(const float4*)p, *(const float4*)(p + 4));
      #pragma unroll
      for (int mt = 0; mt < 2; ++mt)
        hc[mt][nt] = __builtin_amdgcn_mfma_f32_16x16x32_bf16(xa[mt][kk], wb, hc[mt][nt], 0, 0, 0);
    }
  #pragma unroll
  for (int mt = 0; mt < 2; ++mt)
    #pragma unroll
    for (int nt = 0; nt < 4; ++nt) {
      uint2 pk;
      pk.x = cvtpk(hc[mt][nt][0], hc[mt][nt][1]);
      pk.y = cvtpk(hc[mt][nt][2], hc[mt][nt][3]);
      *(uint2*)&hT[(nt * 16 + lr) * 40 + mt * 16 + lk * 4] = pk;
    }
  asm volatile("" ::: "memory");

  bf16x8_t aj[2];
  #pragma unroll
  for (int mt = 0; mt < 2; ++mt)
    aj[mt] = *(const bf16x8_t*)&adjb[(mt * 16 + lr) * 40 + lk * 8];
  f32x4_t oc[2][4];
  #pragma unroll
  for (int mt = 0; mt < 2; ++mt)
    #pragma unroll
    for (int nt = 0; nt < 4; ++nt) oc[mt][nt] = (f32x4_t){0.f, 0.f, 0.f, 0.f};
  #pragma unroll
  for (int nt = 0; nt < 4; ++nt) {
    const bf16x8_t hb = *(const bf16x8_t*)&hT[(nt * 16 + lr) * 40 + lk * 8];
    #pragma unroll
    for (int mt = 0; mt < 2; ++mt)
      oc[mt][nt] = __builtin_amdgcn_mfma_f32_16x16x32_bf16(aj[mt], hb, oc[mt][nt], 0, 0, 0);
  }
  asm volatile("" ::: "memory");

  #pragma unroll
  for (int nt = 0; nt < 4; ++nt) {
    const float bcv = bc[nt * 16 + lr];
    #pragma unroll
    for (int mt = 0; mt < 2; ++mt) {
      float v0 = fmaxf(oc[mt][nt][0] + bcv, 0.0f);
      float v1 = fmaxf(oc[mt][nt][1] + bcv, 0.0f);
      float v2 = fmaxf(oc[mt][nt][2] + bcv, 0.0f);
      float v3 = fmaxf(oc[mt][nt][3] + bcv, 0.0f);
      uint2 pk;
      pk.x = cvtpk(v0, v1);
      pk.y = cvtpk(v2, v3);
      *(uint2*)&outT[(nt * 16 + lr) * 40 + mt * 16 + lk * 4] = pk;
    }
  }
  asm volatile("" ::: "memory");

  unsigned short* og = abf + (size_t)g * HIDDIM;
  #pragma unroll
  for (int j = 0; j < 4; ++j) {
    const int e = lane * 8 + j * 512;
    const int feat = e >> 5, nb = e & 31;
    *(u16x8_t*)(og + e) = *(const u16x8_t*)&outT[feat * 40 + nb];
  }
}

// ---------------------------------------------------------------------------
// Kernel 3: lin1 GEMM  C = relu(A @ W1^T + b1) -> bf16 out
// 32x32x16 MFMA + FRAGMENT-MAJOR LDS (conflict-free linear reads, no swizzle).
// Same 4-phase/tile schedule, stage/gate ledger, vmcnt(4) placement as r4-r6.
// Phases: mt0|mt1|mt2|mt3, each x {nt0,nt1} x 4 ks (8 MFMA/phase).
// ---------------------------------------------------------------------------
__global__ __launch_bounds__(512, 1) void lin1_kernel(const unsigned short* __restrict__ A,
                                                      const unsigned short* __restrict__ Bw,
                                                      const float* __restrict__ b1,
                                                      unsigned short* __restrict__ C) {
  __shared__ __align__(16) unsigned short sh[65536];   // 128 KB

  const int bid = blockIdx.x;
  const int xcd = bid & 7;
  const int g = bid >> 3;
  const int bm = xcd * 8 + (g >> 3);
  const int bn = g & 7;

  const int tid = threadIdx.x;
  const int lane = tid & 63, w = tid >> 6;
  const int wm = w >> 2, wn = w & 3;       // 2 M-waves x 4 N-waves
  const int l31 = lane & 31, lhi = lane >> 5;

  // fragment-major staging: per 128x64 half, slot s = (mt*4+ks)*64 + l (16B each)
  // thread tid -> slots {tid, tid+512}; slot tid+512 differs only by mt+2 (+64 rows)
  const int sl_l  = tid & 63;
  const int sl_mt = tid >> 8;              // 0..1
  const int sl_ks = (tid >> 6) & 3;
  const int srow = sl_mt * 32 + (sl_l & 31);       // row within 128-row half
  const int skel = sl_ks * 16 + (sl_l >> 5) * 8;   // k elem within 64-k tile
  const unsigned short* gA = A  + (size_t)(bm * 256 + srow) * HIDDIM + skel;
  const unsigned short* gB = Bw + (size_t)(bn * 256 + srow) * HIDDIM + skel;

  auto stage = [&](const unsigned short* gb, int d, int mat, int half, int tile) {
    const unsigned short* s = gb + (size_t)(half * 128) * HIDDIM + tile * 64;
    unsigned short* l = &sh[d * 32768 + mat * 16384 + half * 8192 + tid * 8];
    GLDS(s, l);
    GLDS(s + (size_t)64 * HIDDIM, l + 4096);
  };

  // read bases (ushort units): A-frag(mt,ks) = dof + abase + (mt*4+ks)*512
  const int abase = wm * 8192 + lane * 8;
  // B-frag(nt,ks) = dof + 16384 + (wn>>1)*8192 + ((wn&1)*2+nt)*2048 + ks*512 + lane*8
  const int bbase = 16384 + (wn >> 1) * 8192 + (wn & 1) * 4096 + lane * 8;

  f32x16_t acc[4][2];
  #pragma unroll
  for (int i = 0; i < 4; ++i)
    #pragma unroll
    for (int j = 0; j < 2; ++j)
      #pragma unroll
      for (int r = 0; r < 16; ++r) acc[i][j][r] = 0.f;

  // ---- prologue: tile0 (A+B) -> dbuf0, tile1 B -> dbuf1; gate; barrier
  stage(gA, 0, 0, 0, 0); stage(gA, 0, 0, 1, 0);
  stage(gB, 0, 1, 0, 0); stage(gB, 0, 1, 1, 0);
  stage(gB, 1, 1, 0, 1); stage(gB, 1, 1, 1, 1);
  asm volatile("s_waitcnt vmcnt(4)" ::: "memory");
  __builtin_amdgcn_sched_barrier(0);
  __builtin_amdgcn_s_barrier();

  bf16x8_t af[4], bv[2][4];

  for (int it = 0; it < 16; ++it) {
    const int o = 2 * it + 1;
    const bool more = (it < 15);

    #pragma unroll
    for (int half = 0; half < 2; ++half) {
      const int dof = half * 32768;

      // ---- phase 0: read af(mt0) + ALL B frags; stage A-half0
      #pragma unroll
      for (int ks = 0; ks < 4; ++ks)
        af[ks] = *(const bf16x8_t*)&sh[dof + abase + ks * 512];
      #pragma unroll
      for (int nt = 0; nt < 2; ++nt)
        #pragma unroll
        for (int ks = 0; ks < 4; ++ks)
          bv[nt][ks] = *(const bf16x8_t*)&sh[dof + bbase + nt * 2048 + ks * 512];
      if (half == 0) stage(gA, 1, 0, 0, o);
      else if (more) stage(gA, 0, 0, 0, o + 1);
      asm volatile("s_waitcnt lgkmcnt(0)" ::: "memory");
      __builtin_amdgcn_sched_barrier(0);
      __builtin_amdgcn_s_barrier();
      __builtin_amdgcn_s_setprio(1);
      #pragma unroll
      for (int ks = 0; ks < 4; ++ks)
        #pragma unroll
        for (int nt = 0; nt < 2; ++nt)
          acc[0][nt] = __builtin_amdgcn_mfma_f32_32x32x16_bf16(af[ks], bv[nt][ks], acc[0][nt], 0, 0, 0);
      __builtin_amdgcn_s_setprio(0);

      // ---- phases 1..3: read af(mt); stage per ledger; MFMA mt x {nt0,nt1}
      #pragma unroll
      for (int mt = 1; mt < 4; ++mt) {
        #pragma unroll
        for (int ks = 0; ks < 4; ++ks)
          af[ks] = *(const bf16x8_t*)&sh[dof + abase + (mt * 4 + ks) * 512];
        if (mt == 1) {
          if (half == 0) stage(gA, 1, 0, 1, o);
          else if (more) stage(gA, 0, 0, 1, o + 1);
        } else if (mt == 2) {
          if (more) stage(gB, half, 1, 0, (half == 0) ? (o + 1) : (o + 2));
        } else {
          if (more) stage(gB, half, 1, 1, (half == 0) ? (o + 1) : (o + 2));
        }
        asm volatile("s_waitcnt lgkmcnt(0)" ::: "memory");
        if (mt == 3) {
          if (more) { asm volatile("s_waitcnt vmcnt(4)" ::: "memory"); }
          else      { asm volatile("s_waitcnt vmcnt(0)" ::: "memory"); }
        }
        __builtin_amdgcn_sched_barrier(0);
        __builtin_amdgcn_s_barrier();
        __builtin_amdgcn_s_setprio(1);
        #pragma unroll
        for (int ks = 0; ks < 4; ++ks)
          #pragma unroll
          for (int nt = 0; nt < 2; ++nt)
            acc[mt][nt] = __builtin_amdgcn_mfma_f32_32x32x16_bf16(af[ks], bv[nt][ks], acc[mt][nt], 0, 0, 0);
        __builtin_amdgcn_s_setprio(0);
      }
    }
  }

  // ---- epilogue: + b1, relu, bf16 store
  // C/D 32x32 map: col = lane&31, row = (reg&3) + 8*(reg>>2) + 4*(lane>>5)
  const int crow0 = bm * 256 + wm * 128;
  const int ccol0 = bn * 256 + wn * 64;
  float b1v[2];
  b1v[0] = b1[ccol0 + l31];
  b1v[1] = b1[ccol0 + 32 + l31];
  #pragma unroll
  for (int mt = 0; mt < 4; ++mt)
    #pragma unroll
    for (int nt = 0; nt < 2; ++nt) {
      #pragma unroll
      for (int r = 0; r < 16; ++r) {
        const int row = crow0 + mt * 32 + (r & 3) + 8 * (r >> 2) + 4 * lhi;
        const float v = acc[mt][nt][r] + b1v[nt];
        C[(size_t)row * HIDDIM + ccol0 + nt * 32 + l31] = f2bf(v > 0.0f ? v : 0.0f);
      }
    }
}

// ---------------------------------------------------------------------------
// Kernel 4: lin2 (2 dots of 2048, bf16 h1) + softmax; one wave per graph
// ---------------------------------------------------------------------------
__global__ __launch_bounds__(256) void lin2_kernel(const unsigned short* __restrict__ h1,
                                                   const float* __restrict__ W2,
                                                   const float* __restrict__ b2,
                                                   float* __restrict__ out) {
  const int gid = blockIdx.x * 4 + (threadIdx.x >> 6);
  const int lane = threadIdx.x & 63;
  const u16x8_t* hp = (const u16x8_t*)(h1 + (size_t)gid * HIDDIM);
  const float4* w0 = (const float4*)W2;
  const float4* w1 = (const float4*)(W2 + HIDDIM);
  float s0 = 0.0f, s1 = 0.0f;
  #pragma unroll
  for (int i = 0; i < 4; ++i) {
    const int idx = i * 64 + lane;
    const u16x8_t hv = hp[idx];
    const float4 a0 = w0[2 * idx], a1 = w0[2 * idx + 1];
    const float4 b0 = w1[2 * idx], b1 = w1[2 * idx + 1];
    const float f0 = bf2f(hv[0]), f1 = bf2f(hv[1]), f2 = bf2f(hv[2]), f3 = bf2f(hv[3]);
    const float f4 = bf2f(hv[4]), f5 = bf2f(hv[5]), f6 = bf2f(hv[6]), f7 = bf2f(hv[7]);
    s0 += f0 * a0.x + f1 * a0.y + f2 * a0.z + f3 * a0.w
        + f4 * a1.x + f5 * a1.y + f6 * a1.z + f7 * a1.w;
    s1 += f0 * b0.x + f1 * b0.y + f2 * b0.z + f3 * b0.w
        + f4 * b1.x + f5 * b1.y + f6 * b1.z + f7 * b1.w;
  }
  #pragma unroll
  for (int off = 32; off > 0; off >>= 1) {
    s0 += __shfl_down(s0, off);
    s1 += __shfl_down(s1, off);
  }
  if (lane == 0) {
    const float l0 = s0 + b2[0];
    const float l1 = s1 + b2[1];
    const float mx = fmaxf(l0, l1);
    const float e0 = expf(l0 - mx);
    const float e1 = expf(l1 - mx);
    const float inv = 1.0f / (e0 + e1);
    out[(size_t)gid * 2]     = e0 * inv;
    out[(size_t)gid * 2 + 1] = e1 * inv;
  }
}

// ---------------------------------------------------------------------------
extern "C" void kernel_launch(void* const* d_in, const int* in_sizes, int n_in,
                              void* d_out, int out_size, void* d_ws, size_t ws_size,
                              hipStream_t stream) {
  const float* x  = (const float*)d_in[0];
  const float* Wc = (const float*)d_in[1];
  const float* bc = (const float*)d_in[2];
  const float* W1 = (const float*)d_in[3];
  const float* b1 = (const float*)d_in[4];
  const float* W2 = (const float*)d_in[5];
  const float* b2 = (const float*)d_in[6];
  const int* ei   = (const int*)d_in[7];

  // workspace: [0,64MB) Abf bf16 (graph-transposed); [64,72MB) W1bf bf16
  // (col-permuted to match); [72,136MB) h1 bf16
  unsigned short* Abf  = (unsigned short*)d_ws;
  unsigned short* W1bf = (unsigned short*)((char*)d_ws + (size_t)67108864);
  unsigned short* h1   = (unsigned short*)((char*)d_ws + (size_t)75497472);

  cvt_w1<<<dim3(2048), dim3(256), 0, stream>>>(W1, W1bf);
  gcn_kernel<<<dim3(NGRAPH / 4), dim3(256), 0, stream>>>(x, Wc, bc, ei, Abf);
  lin1_kernel<<<dim3(512), dim3(512), 0, stream>>>(Abf, W1bf, b1, h1);
  lin2_kernel<<<dim3(4096), dim3(256), 0, stream>>>(h1, W2, b2, (float*)d_out);
}

// Round 8
// 192.338 us; speedup vs baseline: 1.1003x; 1.1003x over previous
//
#include <hip/hip_runtime.h>

#define NGRAPH 16384
#define NNODE  32
#define EMB    64
#define HIDDIM 2048
#define ETOT   4194304      // NTOT * 8
#define EPG    256          // edges per graph (contiguous block per graph)

typedef __attribute__((ext_vector_type(8))) short bf16x8_t;
typedef __attribute__((ext_vector_type(8))) unsigned short u16x8_t;
typedef __attribute__((ext_vector_type(4))) float f32x4_t;

__device__ __forceinline__ unsigned short f2bf(float v) {
  unsigned int u = __float_as_uint(v);
  u += 0x7fffu + ((u >> 16) & 1u);
  return (unsigned short)(u >> 16);
}
__device__ __forceinline__ float bf2f(unsigned short u) {
  return __uint_as_float(((unsigned int)u) << 16);
}
__device__ __forceinline__ unsigned int cvtpk(float lo, float hi) {
  unsigned int r;
  asm("v_cvt_pk_bf16_f32 %0, %1, %2" : "=v"(r) : "v"(lo), "v"(hi));
  return r;
}
__device__ __forceinline__ bf16x8_t pack8(float4 a, float4 b) {
  union { unsigned int u[4]; bf16x8_t v; } r;
  r.u[0] = cvtpk(a.x, a.y); r.u[1] = cvtpk(a.z, a.w);
  r.u[2] = cvtpk(b.x, b.y); r.u[3] = cvtpk(b.z, b.w);
  return r.v;
}

#define GLDS(SRC, DST)                                                          \
  __builtin_amdgcn_global_load_lds(                                             \
      (const __attribute__((address_space(1))) void*)(SRC),                     \
      (__attribute__((address_space(3))) void*)(DST), 16, 0, 0)

// ---------------------------------------------------------------------------
// Kernel 1: W1 fp32 -> bf16 with column permutation k' = feat*32+node
// ---------------------------------------------------------------------------
__global__ __launch_bounds__(256) void cvt_w1(const float* __restrict__ W,
                                              unsigned short* __restrict__ Wb) {
  __shared__ float row[HIDDIM];
  const int r = blockIdx.x, t = threadIdx.x;
  const float4* p = (const float4*)(W + (size_t)r * HIDDIM);
  *(float4*)&row[t * 8]     = p[t * 2];
  *(float4*)&row[t * 8 + 4] = p[t * 2 + 1];
  __syncthreads();
  const int feat = t >> 2, nb = (t & 3) * 8;   // k' = t*8+j -> feat fixed, node nb+j
  u16x8_t o;
  #pragma unroll
  for (int j = 0; j < 8; ++j) o[j] = f2bf(row[(nb + j) * 64 + feat]);
  *(u16x8_t*)(Wb + (size_t)r * HIDDIM + t * 8) = o;
}

// ---------------------------------------------------------------------------
// Kernel 2: fused GCNConv + ReLU, ONE WAVE PER GRAPH (unchanged from round 6)
// ---------------------------------------------------------------------------
__global__ __launch_bounds__(256, 4) void gcn_kernel(const float* __restrict__ x,
                                                     const float* __restrict__ Wc,
                                                     const float* __restrict__ bc,
                                                     const int* __restrict__ ei,
                                                     unsigned short* __restrict__ abf) {
  __shared__ __align__(16) char smem[40960];     // 4 waves x 10240 B
  const int wv = threadIdx.x >> 6, lane = threadIdx.x & 63;
  const int g = blockIdx.x * 4 + wv;
  char* my = smem + wv * 10240;
  unsigned int*   adjcnt = (unsigned int*)my;            // u32 [32][32], 4096B
  unsigned short* adjb   = (unsigned short*)my;          // bf16 [32][40] (overlays)
  unsigned short* outT   = (unsigned short*)my;          // bf16 [64][40] (overlays)
  unsigned short* hT     = (unsigned short*)(my + 5120); // bf16 [64][40]
  const int lr = lane & 15, lk = lane >> 4;

  const float* xg = x + (size_t)g * (NNODE * EMB);
  float4 xr[2][2][2];
  #pragma unroll
  for (int mt = 0; mt < 2; ++mt)
    #pragma unroll
    for (int kk = 0; kk < 2; ++kk) {
      const float* p = xg + (mt * 16 + lr) * EMB + kk * 32 + lk * 8;
      xr[mt][kk][0] = *(const float4*)p;
      xr[mt][kk][1] = *(const float4*)(p + 4);
    }

  int sl[4], dl[4];
  #pragma unroll
  for (int j = 0; j < 4; ++j) {
    sl[j] = ei[(size_t)g * EPG + j * 64 + lane] - g * NNODE;
    dl[j] = ei[(size_t)ETOT + (size_t)g * EPG + j * 64 + lane] - g * NNODE;
  }

  {
    uint4 z = {0u, 0u, 0u, 0u};
    #pragma unroll
    for (int i = 0; i < 4; ++i) *(uint4*)&adjcnt[lane * 16 + i * 4] = z;
  }
  asm volatile("" ::: "memory");
  #pragma unroll
  for (int j = 0; j < 4; ++j) atomicAdd(&adjcnt[dl[j] * 32 + sl[j]], 1u);
  asm volatile("" ::: "memory");

  const int rr = lane >> 1, hh = lane & 1;
  uint4 c[4];
  unsigned int cs = 0;
  #pragma unroll
  for (int i = 0; i < 4; ++i) {
    c[i] = *(const uint4*)&adjcnt[rr * 32 + hh * 16 + i * 4];
    cs += c[i].x + c[i].y + c[i].z + c[i].w;
  }
  cs += (unsigned int)__shfl_xor((int)cs, 1);
  const float dinvr = rsqrtf(1.0f + (float)cs);
  asm volatile("" ::: "memory");
  {
    float vals[16];
    #pragma unroll
    for (int i = 0; i < 4; ++i) {
      const unsigned int cc[4] = {c[i].x, c[i].y, c[i].z, c[i].w};
      #pragma unroll
      for (int e = 0; e < 4; ++e) {
        const int s = hh * 16 + i * 4 + e;
        const float ds = __shfl(dinvr, s * 2);
        const float cnt = (float)cc[e] + ((s == rr) ? 1.0f : 0.0f);
        vals[i * 4 + e] = cnt * dinvr * ds;
      }
    }
    union { unsigned int u[8]; u16x8_t v[2]; } pk;
    #pragma unroll
    for (int i = 0; i < 8; ++i) pk.u[i] = cvtpk(vals[2 * i], vals[2 * i + 1]);
    *(u16x8_t*)&adjb[rr * 40 + hh * 16]     = pk.v[0];
    *(u16x8_t*)&adjb[rr * 40 + hh * 16 + 8] = pk.v[1];
  }

  bf16x8_t xa[2][2];
  #pragma unroll
  for (int mt = 0; mt < 2; ++mt)
    #pragma unroll
    for (int kk = 0; kk < 2; ++kk) xa[mt][kk] = pack8(xr[mt][kk][0], xr[mt][kk][1]);
  f32x4_t hc[2][4];
  #pragma unroll
  for (int mt = 0; mt < 2; ++mt)
    #pragma unroll
    for (int nt = 0; nt < 4; ++nt) hc[mt][nt] = (f32x4_t){0.f, 0.f, 0.f, 0.f};
  #pragma unroll
  for (int nt = 0; nt < 4; ++nt)
    #pragma unroll
    for (int kk = 0; kk < 2; ++kk) {
      const float* p = Wc + (nt * 16 + lr) * EMB + kk * 32 + lk * 8;
      const bf16x8_t wb = pack8(*(const float4*)p, *(const float4*)(p + 4));
      #pragma unroll
      for (int mt = 0; mt < 2; ++mt)
        hc[mt][nt] = __builtin_amdgcn_mfma_f32_16x16x32_bf16(xa[mt][kk], wb, hc[mt][nt], 0, 0, 0);
    }
  #pragma unroll
  for (int mt = 0; mt < 2; ++mt)
    #pragma unroll
    for (int nt = 0; nt < 4; ++nt) {
      uint2 pk;
      pk.x = cvtpk(hc[mt][nt][0], hc[mt][nt][1]);
      pk.y = cvtpk(hc[mt][nt][2], hc[mt][nt][3]);
      *(uint2*)&hT[(nt * 16 + lr) * 40 + mt * 16 + lk * 4] = pk;
    }
  asm volatile("" ::: "memory");

  bf16x8_t aj[2];
  #pragma unroll
  for (int mt = 0; mt < 2; ++mt)
    aj[mt] = *(const bf16x8_t*)&adjb[(mt * 16 + lr) * 40 + lk * 8];
  f32x4_t oc[2][4];
  #pragma unroll
  for (int mt = 0; mt < 2; ++mt)
    #pragma unroll
    for (int nt = 0; nt < 4; ++nt) oc[mt][nt] = (f32x4_t){0.f, 0.f, 0.f, 0.f};
  #pragma unroll
  for (int nt = 0; nt < 4; ++nt) {
    const bf16x8_t hb = *(const bf16x8_t*)&hT[(nt * 16 + lr) * 40 + lk * 8];
    #pragma unroll
    for (int mt = 0; mt < 2; ++mt)
      oc[mt][nt] = __builtin_amdgcn_mfma_f32_16x16x32_bf16(aj[mt], hb, oc[mt][nt], 0, 0, 0);
  }
  asm volatile("" ::: "memory");

  #pragma unroll
  for (int nt = 0; nt < 4; ++nt) {
    const float bcv = bc[nt * 16 + lr];
    #pragma unroll
    for (int mt = 0; mt < 2; ++mt) {
      float v0 = fmaxf(oc[mt][nt][0] + bcv, 0.0f);
      float v1 = fmaxf(oc[mt][nt][1] + bcv, 0.0f);
      float v2 = fmaxf(oc[mt][nt][2] + bcv, 0.0f);
      float v3 = fmaxf(oc[mt][nt][3] + bcv, 0.0f);
      uint2 pk;
      pk.x = cvtpk(v0, v1);
      pk.y = cvtpk(v2, v3);
      *(uint2*)&outT[(nt * 16 + lr) * 40 + mt * 16 + lk * 4] = pk;
    }
  }
  asm volatile("" ::: "memory");

  unsigned short* og = abf + (size_t)g * HIDDIM;
  #pragma unroll
  for (int j = 0; j < 4; ++j) {
    const int e = lane * 8 + j * 512;
    const int feat = e >> 5, nb = e & 31;
    *(u16x8_t*)(og + e) = *(const u16x8_t*)&outT[feat * 40 + nb];
  }
}

// ---------------------------------------------------------------------------
// Kernel 3: lin1 GEMM  C = relu(A @ W1^T + b1) -> bf16 out
// Round-6 structure (16x16x32, XOR-swizzle, 8-phase, vmcnt(4) ledger) +
// phase-3 READ-AHEAD: next half's A0 quadrant ds_reads issued in the phase-3
// MFMA shadow (ledger-verified: after ph3's vmcnt(4)+barrier, next-half A is
// staged). Phase 0 then reads only B0.
// ---------------------------------------------------------------------------
__global__ __launch_bounds__(512, 1) void lin1_kernel(const unsigned short* __restrict__ A,
                                                      const unsigned short* __restrict__ Bw,
                                                      const float* __restrict__ b1,
                                                      unsigned short* __restrict__ C) {
  __shared__ __align__(16) unsigned short sh[65536];   // 128 KB

  const int bid = blockIdx.x;
  const int xcd = bid & 7;
  const int g = bid >> 3;                  // 0..63 within XCD
  const int bm = xcd * 8 + (g >> 3);
  const int bn = g & 7;

  const int tid = threadIdx.x;
  const int lane = tid & 63, w = tid >> 6;
  const int wm = w >> 2, wn = w & 3;       // 2 M-waves x 4 N-waves
  const int lr = lane & 15, lk = lane >> 4;

  const int r0 = tid >> 3;
  const int kge = ((((tid & 7) * 16) ^ ((r0 & 7) << 4)) >> 1);  // swizzled elem
  const unsigned short* gA = A  + (size_t)(bm * 256 + r0) * HIDDIM + kge;
  const unsigned short* gB = Bw + (size_t)(bn * 256 + r0) * HIDDIM + kge;

  auto stage = [&](const unsigned short* gb, int d, int mat, int half, int tile) {
    const unsigned short* s = gb + (size_t)(half * 128) * HIDDIM + tile * 64;
    unsigned short* l = &sh[d * 32768 + mat * 16384 + half * 8192 + tid * 8];
    GLDS(s, l);
    GLDS(s + (size_t)64 * HIDDIM, l + 4096);
  };

  const int arow = wm * 8192 + lr * 64;
  const int brow = 16384 + (wn >> 1) * 8192 + ((wn & 1) * 64 + lr) * 64;
  int eoff[2];
  eoff[0] = (lk * 8) ^ ((lr & 7) << 3);
  eoff[1] = (32 + lk * 8) ^ ((lr & 7) << 3);

  f32x4_t acc[8][4];
  #pragma unroll
  for (int i = 0; i < 8; ++i)
    #pragma unroll
    for (int j = 0; j < 4; ++j) acc[i][j] = (f32x4_t){0.f, 0.f, 0.f, 0.f};

  // ---- prologue: tile0 (A+B) -> dbuf0, tile1 B -> dbuf1; gate; barrier
  stage(gA, 0, 0, 0, 0); stage(gA, 0, 0, 1, 0);
  stage(gB, 0, 1, 0, 0); stage(gB, 0, 1, 1, 0);
  stage(gB, 1, 1, 0, 1); stage(gB, 1, 1, 1, 1);
  asm volatile("s_waitcnt vmcnt(4)" ::: "memory");
  __builtin_amdgcn_sched_barrier(0);
  __builtin_amdgcn_s_barrier();

  bf16x8_t af[4][2], afn[4][2], bv0[2][2], bv1[2][2];

  // initial A0 quadrant of dbuf0 (guaranteed staged by the prologue gate)
  #pragma unroll
  for (int mi = 0; mi < 4; ++mi) {
    af[mi][0] = *(const bf16x8_t*)&sh[arow + mi * 1024 + eoff[0]];
    af[mi][1] = *(const bf16x8_t*)&sh[arow + mi * 1024 + eoff[1]];
  }

  for (int it = 0; it < 16; ++it) {
    const int o = 2 * it + 1;
    const bool more = (it < 15);

    #pragma unroll
    for (int half = 0; half < 2; ++half) {
      const int dof = half * 32768;

      // ---- phase 0: read B0 (A0 already in af via read-ahead); stage A-half0
      #pragma unroll
      for (int ni = 0; ni < 2; ++ni) {
        bv0[ni][0] = *(const bf16x8_t*)&sh[dof + brow + ni * 1024 + eoff[0]];
        bv0[ni][1] = *(const bf16x8_t*)&sh[dof + brow + ni * 1024 + eoff[1]];
      }
      if (half == 0) stage(gA, 1, 0, 0, o);
      else if (more) stage(gA, 0, 0, 0, o + 1);
      asm volatile("s_waitcnt lgkmcnt(0)" ::: "memory");
      __builtin_amdgcn_sched_barrier(0);
      __builtin_amdgcn_s_barrier();
      __builtin_amdgcn_s_setprio(1);
      #pragma unroll
      for (int kk = 0; kk < 2; ++kk)
        #pragma unroll
        for (int mi = 0; mi < 4; ++mi)
          #pragma unroll
          for (int ni = 0; ni < 2; ++ni)
            acc[mi][ni] = __builtin_amdgcn_mfma_f32_16x16x32_bf16(af[mi][kk], bv0[ni][kk], acc[mi][ni], 0, 0, 0);
      __builtin_amdgcn_s_setprio(0);

      // ---- phase 1: read B1; stage A-half1
      #pragma unroll
      for (int ni = 0; ni < 2; ++ni) {
        bv1[ni][0] = *(const bf16x8_t*)&sh[dof + brow + (ni + 2) * 1024 + eoff[0]];
        bv1[ni][1] = *(const bf16x8_t*)&sh[dof + brow + (ni + 2) * 1024 + eoff[1]];
      }
      if (half == 0) stage(gA, 1, 0, 1, o);
      else if (more) stage(gA, 0, 0, 1, o + 1);
      asm volatile("s_waitcnt lgkmcnt(0)" ::: "memory");
      __builtin_amdgcn_sched_barrier(0);
      __builtin_amdgcn_s_barrier();
      __builtin_amdgcn_s_setprio(1);
      #pragma unroll
      for (int kk = 0; kk < 2; ++kk)
        #pragma unroll
        for (int mi = 0; mi < 4; ++mi)
          #pragma unroll
          for (int ni = 0; ni < 2; ++ni)
            acc[mi][ni + 2] = __builtin_amdgcn_mfma_f32_16x16x32_bf16(af[mi][kk], bv1[ni][kk], acc[mi][ni + 2], 0, 0, 0);
      __builtin_amdgcn_s_setprio(0);

      // ---- phase 2: read A1 quadrant; stage B-half0 of tile+2
      #pragma unroll
      for (int mi = 0; mi < 4; ++mi) {
        af[mi][0] = *(const bf16x8_t*)&sh[dof + arow + (mi + 4) * 1024 + eoff[0]];
        af[mi][1] = *(const bf16x8_t*)&sh[dof + arow + (mi + 4) * 1024 + eoff[1]];
      }
      if (more) stage(gB, half, 1, 0, (half == 0) ? (o + 1) : (o + 2));
      asm volatile("s_waitcnt lgkmcnt(0)" ::: "memory");
      __builtin_amdgcn_sched_barrier(0);
      __builtin_amdgcn_s_barrier();
      __builtin_amdgcn_s_setprio(1);
      #pragma unroll
      for (int kk = 0; kk < 2; ++kk)
        #pragma unroll
        for (int mi = 0; mi < 4; ++mi)
          #pragma unroll
          for (int ni = 0; ni < 2; ++ni)
            acc[mi + 4][ni + 2] = __builtin_amdgcn_mfma_f32_16x16x32_bf16(af[mi][kk], bv1[ni][kk], acc[mi + 4][ni + 2], 0, 0, 0);
      __builtin_amdgcn_s_setprio(0);

      // ---- phase 3: stage B-half1 of tile+2; vmcnt gate + barrier;
      //      READ-AHEAD next half's A0 quadrant in the MFMA shadow
      if (more) stage(gB, half, 1, 1, (half == 0) ? (o + 1) : (o + 2));
      asm volatile("s_waitcnt lgkmcnt(0)" ::: "memory");
      if (more) { asm volatile("s_waitcnt vmcnt(4)" ::: "memory"); }
      else      { asm volatile("s_waitcnt vmcnt(0)" ::: "memory"); }
      __builtin_amdgcn_sched_barrier(0);
      __builtin_amdgcn_s_barrier();
      __builtin_amdgcn_sched_barrier(0);   // pin read-ahead BELOW the barrier
      if (half == 0 || more) {
        const int ndof = 32768 - dof;      // next half's dbuf
        #pragma unroll
        for (int mi = 0; mi < 4; ++mi) {
          afn[mi][0] = *(const bf16x8_t*)&sh[ndof + arow + mi * 1024 + eoff[0]];
          afn[mi][1] = *(const bf16x8_t*)&sh[ndof + arow + mi * 1024 + eoff[1]];
        }
      }
      __builtin_amdgcn_s_setprio(1);
      #pragma unroll
      for (int kk = 0; kk < 2; ++kk)
        #pragma unroll
        for (int mi = 0; mi < 4; ++mi)
          #pragma unroll
          for (int ni = 0; ni < 2; ++ni)
            acc[mi + 4][ni] = __builtin_amdgcn_mfma_f32_16x16x32_bf16(af[mi][kk], bv0[ni][kk], acc[mi + 4][ni], 0, 0, 0);
      __builtin_amdgcn_s_setprio(0);
      #pragma unroll
      for (int mi = 0; mi < 4; ++mi) {
        af[mi][0] = afn[mi][0];
        af[mi][1] = afn[mi][1];
      }
    }
  }

  // ---- epilogue: + b1, relu, bf16 store
  const int crow0 = bm * 256 + wm * 128 + lk * 4;
  const int ccol0 = bn * 256 + wn * 64 + lr;
  float b1v[4];
  #pragma unroll
  for (int ni = 0; ni < 4; ++ni) b1v[ni] = b1[ccol0 + ni * 16];
  #pragma unroll
  for (int mi = 0; mi < 8; ++mi)
    #pragma unroll
    for (int r = 0; r < 4; ++r) {
      unsigned short* cp = C + (size_t)(crow0 + mi * 16 + r) * HIDDIM + ccol0;
      #pragma unroll
      for (int ni = 0; ni < 4; ++ni) {
        const float v = acc[mi][ni][r] + b1v[ni];
        cp[ni * 16] = f2bf(v > 0.0f ? v : 0.0f);
      }
    }
}

// ---------------------------------------------------------------------------
// Kernel 4: lin2 (2 dots of 2048, bf16 h1) + softmax; one wave per graph
// ---------------------------------------------------------------------------
__global__ __launch_bounds__(256) void lin2_kernel(const unsigned short* __restrict__ h1,
                                                   const float* __restrict__ W2,
                                                   const float* __restrict__ b2,
                                                   float* __restrict__ out) {
  const int gid = blockIdx.x * 4 + (threadIdx.x >> 6);
  const int lane = threadIdx.x & 63;
  const u16x8_t* hp = (const u16x8_t*)(h1 + (size_t)gid * HIDDIM);
  const float4* w0 = (const float4*)W2;
  const float4* w1 = (const float4*)(W2 + HIDDIM);
  float s0 = 0.0f, s1 = 0.0f;
  #pragma unroll
  for (int i = 0; i < 4; ++i) {
    const int idx = i * 64 + lane;
    const u16x8_t hv = hp[idx];
    const float4 a0 = w0[2 * idx], a1 = w0[2 * idx + 1];
    const float4 b0 = w1[2 * idx], b1 = w1[2 * idx + 1];
    const float f0 = bf2f(hv[0]), f1 = bf2f(hv[1]), f2 = bf2f(hv[2]), f3 = bf2f(hv[3]);
    const float f4 = bf2f(hv[4]), f5 = bf2f(hv[5]), f6 = bf2f(hv[6]), f7 = bf2f(hv[7]);
    s0 += f0 * a0.x + f1 * a0.y + f2 * a0.z + f3 * a0.w
        + f4 * a1.x + f5 * a1.y + f6 * a1.z + f7 * a1.w;
    s1 += f0 * b0.x + f1 * b0.y + f2 * b0.z + f3 * b0.w
        + f4 * b1.x + f5 * b1.y + f6 * b1.z + f7 * b1.w;
  }
  #pragma unroll
  for (int off = 32; off > 0; off >>= 1) {
    s0 += __shfl_down(s0, off);
    s1 += __shfl_down(s1, off);
  }
  if (lane == 0) {
    const float l0 = s0 + b2[0];
    const float l1 = s1 + b2[1];
    const float mx = fmaxf(l0, l1);
    const float e0 = expf(l0 - mx);
    const float e1 = expf(l1 - mx);
    const float inv = 1.0f / (e0 + e1);
    out[(size_t)gid * 2]     = e0 * inv;
    out[(size_t)gid * 2 + 1] = e1 * inv;
  }
}

// ---------------------------------------------------------------------------
extern "C" void kernel_launch(void* const* d_in, const int* in_sizes, int n_in,
                              void* d_out, int out_size, void* d_ws, size_t ws_size,
                              hipStream_t stream) {
  const float* x  = (const float*)d_in[0];
  const float* Wc = (const float*)d_in[1];
  const float* bc = (const float*)d_in[2];
  const float* W1 = (const float*)d_in[3];
  const float* b1 = (const float*)d_in[4];
  const float* W2 = (const float*)d_in[5];
  const float* b2 = (const float*)d_in[6];
  const int* ei   = (const int*)d_in[7];

  // workspace: [0,64MB) Abf bf16 (graph-transposed); [64,72MB) W1bf bf16
  // (col-permuted to match); [72,136MB) h1 bf16
  unsigned short* Abf  = (unsigned short*)d_ws;
  unsigned short* W1bf = (unsigned short*)((char*)d_ws + (size_t)67108864);
  unsigned short* h1   = (unsigned short*)((char*)d_ws + (size_t)75497472);

  cvt_w1<<<dim3(2048), dim3(256), 0, stream>>>(W1, W1bf);
  gcn_kernel<<<dim3(NGRAPH / 4), dim3(256), 0, stream>>>(x, Wc, bc, ei, Abf);
  lin1_kernel<<<dim3(512), dim3(512), 0, stream>>>(Abf, W1bf, b1, h1);
  lin2_kernel<<<dim3(4096), dim3(256), 0, stream>>>(h1, W2, b2, (float*)d_out);
}